// Round 5
// baseline (14.338 us; speedup 1.0000x reference)
//
#include <hip/hip_runtime.h>

constexpr int T    = 512;
constexpr int C    = 512;
constexpr int HALF = 50;
constexpr int W    = 2 * HALF + 1;   // 101
constexpr int RPW  = 4;              // rows (t values) per wave
constexpr int WAVES = 4;             // waves per block

// One 64-lane wave per RPW=4 consecutive (b,t) rows (same b): ctx/mask are
// loaded once per wave and reused across the 4 rows; concepts/tgt_ts for the
// 4 rows come in as uniform int4 (s_load). ~99.9% of gather indices clip to
// 0/100 -> per-row exp(row[0]) / exp(row[100]) scalars; rare interior hits
// take a predicated global gather. 4 independent row pipelines give ILP over
// the butterfly/store latencies. No LDS, no barriers.
__global__ __launch_bounds__(256, 4) void TimeAttention_33715493274067_kernel(
    const int*   __restrict__ concepts,   // [B,T]
    const int*   __restrict__ tgt_ts,     // [B,T]
    const int*   __restrict__ ctx_ts,     // [B,C]
    const int*   __restrict__ mask,       // [B,C]
    const float* __restrict__ emb,        // [V,W]
    const float* __restrict__ bias,       // [W]
    float*       __restrict__ out)        // [B,T,C]
{
    const int tid  = threadIdx.x;
    const int lane = tid & 63;
    // Row-group id, wave-uniform.
    const int g = __builtin_amdgcn_readfirstlane(blockIdx.x * WAVES + (tid >> 6));
    const int b   = g >> 7;               // T/RPW = 128 groups per b
    const int bt0 = b * T + (g & 127) * RPW;

    // Per-lane context loads (shared by all 4 rows): contiguous 1KB/instr.
    const int cbase0 = b * C + lane * 4;
    const int cbase1 = cbase0 + 256;
    const int4 ct0 = *(const int4*)(ctx_ts + cbase0);
    const int4 ct1 = *(const int4*)(ctx_ts + cbase1);
    const int4 mk0 = *(const int4*)(mask   + cbase0);
    const int4 mk1 = *(const int4*)(mask   + cbase1);

    // Uniform per-row metadata: 4 consecutive bt -> one dwordx4 each.
    const int4 cc  = *(const int4*)(concepts + bt0);
    const int4 tts = *(const int4*)(tgt_ts   + bt0);
    const int  ccr[RPW] = {cc.x, cc.y, cc.z, cc.w};
    const int  ttr[RPW] = {tts.x, tts.y, tts.z, tts.w};

    const float b0 = bias[0];
    const float bW = bias[W - 1];

    const int d[8]  = {ct0.x, ct0.y, ct0.z, ct0.w, ct1.x, ct1.y, ct1.z, ct1.w};
    const int mm[8] = {mk0.x, mk0.y, mk0.z, mk0.w, mk1.x, mk1.y, mk1.z, mk1.w};

    #pragma unroll
    for (int r = 0; r < RPW; ++r) {
        const float* erow = emb + (size_t)ccr[r] * W;
        const float eLo = __expf(erow[0]     + b0);
        const float eHi = __expf(erow[W - 1] + bW);
        const int   tt  = ttr[r];

        float e[8];
        float s = 0.0f;
        #pragma unroll
        for (int i = 0; i < 8; ++i) {
            const int idx = min(max(d[i] - tt, -HALF), HALF) + HALF;  // [0,100]
            float v;
            if (__builtin_expect((unsigned)(idx - 1) < 99u, 0)) {
                v = __expf(erow[idx] + bias[idx]);   // rare interior (~0.1%)
            } else {
                v = idx ? eHi : eLo;
            }
            e[i] = mm[i] ? 0.0f : v;                 // masked -> exactly 0
            s += e[i];
        }

        #pragma unroll
        for (int o = 1; o < 64; o <<= 1) s += __shfl_xor(s, o, 64);
        const float inv = __builtin_amdgcn_rcpf(s);

        float4 o0 = {e[0] * inv, e[1] * inv, e[2] * inv, e[3] * inv};
        float4 o1 = {e[4] * inv, e[5] * inv, e[6] * inv, e[7] * inv};
        float* obase = out + (size_t)(bt0 + r) * C;
        *(float4*)(obase + lane * 4)       = o0;     // contiguous 1KB/instr
        *(float4*)(obase + 256 + lane * 4) = o1;
    }
}

extern "C" void kernel_launch(void* const* d_in, const int* in_sizes, int n_in,
                              void* d_out, int out_size, void* d_ws, size_t ws_size,
                              hipStream_t stream) {
    const int*   concepts = (const int*)  d_in[0];
    const int*   tgt_ts   = (const int*)  d_in[1];
    const int*   ctx_ts   = (const int*)  d_in[2];
    const int*   mask     = (const int*)  d_in[3];
    const float* emb      = (const float*)d_in[4];
    const float* bias     = (const float*)d_in[5];
    float*       out      = (float*)      d_out;

    const int n_bt = in_sizes[0];                    // B*T = 16384
    const int grid = n_bt / (RPW * WAVES);           // 1024 blocks
    TimeAttention_33715493274067_kernel<<<grid, 256, 0, stream>>>(
        concepts, tgt_ts, ctx_ts, mask, emb, bias, out);
}